// Round 2
// baseline (2207.447 us; speedup 1.0000x reference)
//
#include <hip/hip_runtime.h>

#define N_NODES 50000
#define D 128
#define R 8
#define E_EDGES 600000
#define TILE_E 128

// ws (int) layout
#define CNT_OFF 0                     // N*R counts per (dst, rel)
#define HIST_OFF (N_NODES * R)        // 8 per-relation edge counts
#define BASE_OFF (N_NODES * R + 8)    // 9 exclusive-scan bases
#define CURSOR_OFF (N_NODES * R + 24) // 8 scatter cursors
#define BUCKET_OFF (N_NODES * R + 32) // E bucketed edge ids
#define MAX_TILES (E_EDGES / TILE_E + R + 1)

__global__ void __launch_bounds__(256)
count_kernel(const int* __restrict__ ei, const int* __restrict__ et, int* ws) {
    __shared__ int whist[4][8];
    int tid = threadIdx.x, wid = tid >> 6, lane = tid & 63;
    int e = blockIdx.x * 256 + tid;
    bool valid = e < E_EDGES;
    int r = -1;
    if (valid) {
        r = et[e];
        int dst = ei[E_EDGES + e];
        atomicAdd(&ws[CNT_OFF + dst * R + r], 1);
    }
#pragma unroll
    for (int rr = 0; rr < 8; ++rr) {
        unsigned long long m = __ballot(r == rr);
        if (lane == 0) whist[wid][rr] = __popcll(m);
    }
    __syncthreads();
    if (tid < 8) {
        int tot = whist[0][tid] + whist[1][tid] + whist[2][tid] + whist[3][tid];
        if (tot) atomicAdd(&ws[HIST_OFF + tid], tot);
    }
}

__global__ void scan_kernel(int* ws) {
    int acc = 0;
    for (int r = 0; r < R; ++r) {
        ws[BASE_OFF + r] = acc;
        ws[CURSOR_OFF + r] = acc;
        acc += ws[HIST_OFF + r];
    }
    ws[BASE_OFF + R] = acc;
}

__global__ void __launch_bounds__(256)
bucket_kernel(const int* __restrict__ et, int* ws) {
    __shared__ int whist[4][8];
    __shared__ int wbase[4][8];
    int tid = threadIdx.x, wid = tid >> 6, lane = tid & 63;
    int e = blockIdx.x * 256 + tid;
    bool valid = e < E_EDGES;
    int r = valid ? et[e] : -1;
    unsigned long long lmlt = ((unsigned long long)1 << lane) - 1;
    int prefix = 0;
#pragma unroll
    for (int rr = 0; rr < 8; ++rr) {
        unsigned long long m = __ballot(r == rr);
        if (lane == 0) whist[wid][rr] = __popcll(m);
        if (r == rr) prefix = __popcll(m & lmlt);
    }
    __syncthreads();
    if (tid < 8) {
        int t0 = whist[0][tid], t1 = whist[1][tid], t2 = whist[2][tid], t3 = whist[3][tid];
        int tot = t0 + t1 + t2 + t3;
        int base = tot ? atomicAdd(&ws[CURSOR_OFF + tid], tot) : 0;
        wbase[0][tid] = base;
        wbase[1][tid] = base + t0;
        wbase[2][tid] = base + t0 + t1;
        wbase[3][tid] = base + t0 + t1 + t2;
    }
    __syncthreads();
    if (valid) ws[BUCKET_OFF + wbase[wid][r] + prefix] = e;
}

// One block: 128 edges x 128 out-cols for one relation. K=128 in chunks of 32.
// Thread (tc=tid&15, tr=tid>>4) computes rows tr*8..+7, cols tc*8..+7.
__global__ void __launch_bounds__(256)
rgemm_kernel(const float* __restrict__ x, const int* __restrict__ ei,
             const float* __restrict__ W, const int* __restrict__ ws,
             float* __restrict__ out) {
    __shared__ int s_base[R + 1];
    __shared__ int esrc[TILE_E];
    __shared__ int edst[TILE_E];
    __shared__ float einv[TILE_E];
    __shared__ __align__(16) float xs[32][132];  // [k][edge], +4 pad
    __shared__ __align__(16) float Wc[32][128];  // [k][col]

    if (threadIdx.x < R + 1) s_base[threadIdx.x] = ws[BASE_OFF + threadIdx.x];
    __syncthreads();

    // map blockIdx -> (relation, local tile)
    int bid = blockIdx.x;
    int rsel = -1, tloc = 0, acc = 0;
#pragma unroll
    for (int r = 0; r < R; ++r) {
        int c = s_base[r + 1] - s_base[r];
        int t = (c + TILE_E - 1) / TILE_E;
        if (rsel < 0 && bid < acc + t) { rsel = r; tloc = bid - acc; }
        acc += t;
    }
    if (rsel < 0) return;  // uniform across block

    int segstart = s_base[rsel] + tloc * TILE_E;
    int nE = s_base[rsel + 1] - segstart;
    if (nE > TILE_E) nE = TILE_E;

    if (threadIdx.x < TILE_E) {
        int i = threadIdx.x;
        if (i < nE) {
            int e = ws[BUCKET_OFF + segstart + i];
            int s = ei[e];
            int dd = ei[E_EDGES + e];
            esrc[i] = s;
            edst[i] = dd;
            int c = ws[CNT_OFF + dd * R + rsel];
            einv[i] = 1.0f / (float)(c > 0 ? c : 1);
        } else {
            esrc[i] = 0;
            edst[i] = -1;
            einv[i] = 0.0f;
        }
    }
    __syncthreads();

    int tc = threadIdx.x & 15;  // cols tc*8 .. +7
    int tr = threadIdx.x >> 4;  // rows tr*8 .. +7
    float accm[8][8];
#pragma unroll
    for (int j = 0; j < 8; ++j)
#pragma unroll
        for (int c = 0; c < 8; ++c) accm[j][c] = 0.0f;

    const float* Wr = W + (size_t)rsel * D * D;

    for (int k0 = 0; k0 < D; k0 += 32) {
        // gather x rows transposed: thread (i=tid>>1, half=tid&1) loads 16 floats
        {
            int i = threadIdx.x >> 1;
            int half = threadIdx.x & 1;
            const float4* xp = (const float4*)(x + (size_t)esrc[i] * D + k0 + half * 16);
            int kb = half * 16;
#pragma unroll
            for (int q = 0; q < 4; ++q) {
                float4 v = xp[q];
                xs[kb + q * 4 + 0][i] = v.x;
                xs[kb + q * 4 + 1][i] = v.y;
                xs[kb + q * 4 + 2][i] = v.z;
                xs[kb + q * 4 + 3][i] = v.w;
            }
        }
        // W chunk: contiguous 32x128 floats
        {
            const float4* s4 = (const float4*)(Wr + (size_t)k0 * D);
            float4* d4 = (float4*)&Wc[0][0];
#pragma unroll
            for (int q = 0; q < 4; ++q)
                d4[threadIdx.x + q * 256] = s4[threadIdx.x + q * 256];
        }
        __syncthreads();
#pragma unroll
        for (int k = 0; k < 32; ++k) {
            float4 a0 = *(const float4*)&xs[k][tr * 8];
            float4 a1 = *(const float4*)&xs[k][tr * 8 + 4];
            float4 b0 = *(const float4*)&Wc[k][tc * 8];
            float4 b1 = *(const float4*)&Wc[k][tc * 8 + 4];
            float a[8] = {a0.x, a0.y, a0.z, a0.w, a1.x, a1.y, a1.z, a1.w};
            float bv[8] = {b0.x, b0.y, b0.z, b0.w, b1.x, b1.y, b1.z, b1.w};
#pragma unroll
            for (int j = 0; j < 8; ++j)
#pragma unroll
                for (int c = 0; c < 8; ++c)
                    accm[j][c] += a[j] * bv[c];
        }
        __syncthreads();
    }

    // scatter: out[dst] += msg * inv_cnt
#pragma unroll
    for (int j = 0; j < 8; ++j) {
        int i = tr * 8 + j;
        if (i < nE) {
            float inv = einv[i];
            float* op = out + (size_t)edst[i] * D + tc * 8;
#pragma unroll
            for (int c = 0; c < 8; ++c) atomicAdd(&op[c], accm[j][c] * inv);
        }
    }
}

// out = relu(out + x @ W_root + b), 64 nodes per block
__global__ void __launch_bounds__(256)
root_kernel(const float* __restrict__ x, const float* __restrict__ Wroot,
            const float* __restrict__ b, float* __restrict__ out) {
    __shared__ __align__(16) float xs[64][33];
    __shared__ __align__(16) float Wc[32][128];
    int n0 = blockIdx.x * 64;
    int tc = threadIdx.x & 15;
    int tr = threadIdx.x >> 4;
    float accm[4][8];
#pragma unroll
    for (int j = 0; j < 4; ++j)
#pragma unroll
        for (int c = 0; c < 8; ++c) accm[j][c] = 0.0f;

    for (int k0 = 0; k0 < D; k0 += 32) {
        {
            int i = threadIdx.x & 63;
            int kq = threadIdx.x >> 6;
            int n = n0 + i;
            if (n >= N_NODES) n = N_NODES - 1;  // clamp (harmless dup load)
            const float* xp = x + (size_t)n * D + k0 + kq * 8;
            float4 v0 = *(const float4*)(xp);
            float4 v1 = *(const float4*)(xp + 4);
            int kb = kq * 8;
            xs[i][kb + 0] = v0.x; xs[i][kb + 1] = v0.y;
            xs[i][kb + 2] = v0.z; xs[i][kb + 3] = v0.w;
            xs[i][kb + 4] = v1.x; xs[i][kb + 5] = v1.y;
            xs[i][kb + 6] = v1.z; xs[i][kb + 7] = v1.w;
        }
        {
            const float4* s4 = (const float4*)(Wroot + (size_t)k0 * D);
            float4* d4 = (float4*)&Wc[0][0];
#pragma unroll
            for (int q = 0; q < 4; ++q)
                d4[threadIdx.x + q * 256] = s4[threadIdx.x + q * 256];
        }
        __syncthreads();
#pragma unroll
        for (int k = 0; k < 32; ++k) {
            float a0 = xs[tr * 4 + 0][k];
            float a1 = xs[tr * 4 + 1][k];
            float a2 = xs[tr * 4 + 2][k];
            float a3 = xs[tr * 4 + 3][k];
            float bv[8];
#pragma unroll
            for (int c = 0; c < 8; ++c) bv[c] = Wc[k][tc * 8 + c];
#pragma unroll
            for (int c = 0; c < 8; ++c) {
                accm[0][c] += a0 * bv[c];
                accm[1][c] += a1 * bv[c];
                accm[2][c] += a2 * bv[c];
                accm[3][c] += a3 * bv[c];
            }
        }
        __syncthreads();
    }

#pragma unroll
    for (int j = 0; j < 4; ++j) {
        int n = n0 + tr * 4 + j;
        if (n < N_NODES) {
            float* op = out + (size_t)n * D + tc * 8;
            const float* bp = b + tc * 8;
#pragma unroll
            for (int c = 0; c < 8; ++c) {
                float v = op[c] + accm[j][c] + bp[c];
                op[c] = v > 0.0f ? v : 0.0f;
            }
        }
    }
}

extern "C" void kernel_launch(void* const* d_in, const int* in_sizes, int n_in,
                              void* d_out, int out_size, void* d_ws, size_t ws_size,
                              hipStream_t stream) {
    const float* x     = (const float*)d_in[0];
    const int*   ei    = (const int*)d_in[1];
    const int*   et    = (const int*)d_in[2];
    const float* W     = (const float*)d_in[3];
    const float* Wroot = (const float*)d_in[4];
    const float* b     = (const float*)d_in[5];
    float* out = (float*)d_out;
    int* ws = (int*)d_ws;

    hipMemsetAsync(d_out, 0, (size_t)N_NODES * D * sizeof(float), stream);
    hipMemsetAsync(d_ws, 0, (size_t)(N_NODES * R + 32) * sizeof(int), stream);

    count_kernel<<<(E_EDGES + 255) / 256, 256, 0, stream>>>(ei, et, ws);
    scan_kernel<<<1, 1, 0, stream>>>(ws);
    bucket_kernel<<<(E_EDGES + 255) / 256, 256, 0, stream>>>(et, ws);
    rgemm_kernel<<<MAX_TILES, 256, 0, stream>>>(x, ei, W, ws, out);
    root_kernel<<<(N_NODES + 63) / 64, 256, 0, stream>>>(x, Wroot, b, out);
}

// Round 3
// 424.242 us; speedup vs baseline: 5.2033x; 5.2033x over previous
//
#include <hip/hip_runtime.h>

#define N_NODES 50000
#define D 128
#define R 8
#define E_EDGES 600000
#define NR (N_NODES * R)                 // 400000 (dst,rel) keys
#define SCAN_BLOCKS ((NR + 1023) / 1024) // 391

// ws layout (ints): [0, NR) = counts -> exclusive offsets -> segment ENDS
//                   [NR, NR+E) = bucket (src node per edge, (dst,rel)-sorted);
//                   scan partials alias the bucket region (used before bucket fill)

__global__ void __launch_bounds__(256)
count_kernel(const int* __restrict__ ei, const int* __restrict__ et,
             int* __restrict__ cnt) {
    int e = blockIdx.x * 256 + threadIdx.x;
    if (e < E_EDGES) {
        int dst = ei[E_EDGES + e];
        int r = et[e];
        atomicAdd(&cnt[dst * R + r], 1);
    }
}

// Block-local exclusive scan over 1024 counts; per-block total -> part[]
__global__ void __launch_bounds__(256)
scan1_kernel(int* __restrict__ off, int* __restrict__ part) {
    __shared__ int wsum[4];
    int tid = threadIdx.x, lane = tid & 63, wid = tid >> 6;
    int base = blockIdx.x * 1024 + tid * 4;
    int c0 = 0, c1 = 0, c2 = 0, c3 = 0;
    if (base + 0 < NR) c0 = off[base + 0];
    if (base + 1 < NR) c1 = off[base + 1];
    if (base + 2 < NR) c2 = off[base + 2];
    if (base + 3 < NR) c3 = off[base + 3];
    int ts = c0 + c1 + c2 + c3;
    int v = ts;
#pragma unroll
    for (int o = 1; o < 64; o <<= 1) {
        int u = __shfl_up(v, o, 64);
        if (lane >= o) v += u;
    }
    if (lane == 63) wsum[wid] = v;
    __syncthreads();
    int wbase = 0;
#pragma unroll
    for (int w = 0; w < 4; ++w)
        if (w < wid) wbase += wsum[w];
    int excl = wbase + v - ts;
    if (base + 0 < NR) off[base + 0] = excl;
    if (base + 1 < NR) off[base + 1] = excl + c0;
    if (base + 2 < NR) off[base + 2] = excl + c0 + c1;
    if (base + 3 < NR) off[base + 3] = excl + c0 + c1 + c2;
    if (tid == 0) part[blockIdx.x] = wsum[0] + wsum[1] + wsum[2] + wsum[3];
}

__global__ void __launch_bounds__(512)
scan2_kernel(int* __restrict__ part) {
    __shared__ int sp[SCAN_BLOCKS];
    int tid = threadIdx.x;
    if (tid < SCAN_BLOCKS) sp[tid] = part[tid];
    __syncthreads();
    if (tid == 0) {
        int acc = 0;
        for (int i = 0; i < SCAN_BLOCKS; ++i) { int t = sp[i]; sp[i] = acc; acc += t; }
    }
    __syncthreads();
    if (tid < SCAN_BLOCKS) part[tid] = sp[tid];
}

__global__ void __launch_bounds__(256)
scan3_kernel(int* __restrict__ off, const int* __restrict__ part) {
    int p = part[blockIdx.x];
    int base = blockIdx.x * 1024 + threadIdx.x * 4;
#pragma unroll
    for (int i = 0; i < 4; ++i)
        if (base + i < NR) off[base + i] += p;
}

// Scatter src ids into (dst,rel)-sorted bucket. Turns off[] into segment ENDS:
// after this kernel, segment k spans [k==0 ? 0 : off[k-1], off[k]).
__global__ void __launch_bounds__(256)
bucket_kernel(const int* __restrict__ ei, const int* __restrict__ et,
              int* __restrict__ off, int* __restrict__ bucket) {
    int e = blockIdx.x * 256 + threadIdx.x;
    if (e < E_EDGES) {
        int src = ei[e];
        int dst = ei[E_EDGES + e];
        int r = et[e];
        int key = dst * R + r;
        int pos = atomicAdd(&off[key], 1);
        bucket[pos] = src;
    }
}

// One block = 64 dst nodes. For r=0..7: A = per-(dst,r) mean of x_src (LDS),
// acc += A @ W[r]. r=8: A = x[dst], acc += A @ W_root. Then +bias, ReLU,
// single non-atomic write of out rows.
__global__ void __launch_bounds__(256, 3)
fused_kernel(const float* __restrict__ x, const float* __restrict__ W,
             const float* __restrict__ Wroot, const float* __restrict__ bias,
             const int* __restrict__ ends, const int* __restrict__ bucket,
             float* __restrict__ out) {
    __shared__ float A[64][129];                  // [dst][k], stride 129: <=2-way banks
    __shared__ __align__(16) float Wc[32][128];   // staged W k-chunk
    __shared__ float bs[128];

    int tid = threadIdx.x;
    if (tid < 128) bs[tid] = bias[tid];
    int tc = tid & 15;        // GEMM: col group (8 cols)
    int tr = tid >> 4;        // GEMM: row group (4 rows)
    int gd = tid >> 2;        // gather: dst slot 0..63
    int gq = tid & 3;         // gather: 32-col quarter
    int n0 = blockIdx.x * 64;

    float acc[4][8];
#pragma unroll
    for (int j = 0; j < 4; ++j)
#pragma unroll
        for (int c = 0; c < 8; ++c) acc[j][c] = 0.0f;

    for (int r = 0; r < 9; ++r) {
        float ga[32];
#pragma unroll
        for (int c = 0; c < 32; ++c) ga[c] = 0.0f;
        int n = n0 + gd;
        if (r < 8) {
            if (n < N_NODES) {
                int key = n * R + r;
                int s = (key == 0) ? 0 : ends[key - 1];
                int epos = ends[key];
                float inv = (epos > s) ? 1.0f / (float)(epos - s) : 0.0f;
                for (int p = s; p < epos; ++p) {
                    int src = bucket[p];
                    const float4* xp = (const float4*)(x + (size_t)src * D + gq * 32);
#pragma unroll
                    for (int u = 0; u < 8; ++u) {
                        float4 v = xp[u];
                        ga[u * 4 + 0] += v.x; ga[u * 4 + 1] += v.y;
                        ga[u * 4 + 2] += v.z; ga[u * 4 + 3] += v.w;
                    }
                }
#pragma unroll
                for (int c = 0; c < 32; ++c) ga[c] *= inv;
            }
        } else {
            if (n < N_NODES) {
                const float4* xp = (const float4*)(x + (size_t)n * D + gq * 32);
#pragma unroll
                for (int u = 0; u < 8; ++u) {
                    float4 v = xp[u];
                    ga[u * 4 + 0] = v.x; ga[u * 4 + 1] = v.y;
                    ga[u * 4 + 2] = v.z; ga[u * 4 + 3] = v.w;
                }
            }
        }
        __syncthreads();  // previous rel's GEMM done reading A/Wc
#pragma unroll
        for (int c = 0; c < 32; ++c) A[gd][gq * 32 + c] = ga[c];
        __syncthreads();

        const float* Wr = (r < 8) ? (W + (size_t)r * D * D) : Wroot;
        for (int k0 = 0; k0 < D; k0 += 32) {
            const float4* s4 = (const float4*)(Wr + (size_t)k0 * D);
            float4* d4 = (float4*)&Wc[0][0];
#pragma unroll
            for (int u = 0; u < 4; ++u) d4[tid + u * 256] = s4[tid + u * 256];
            __syncthreads();
#pragma unroll
            for (int k = 0; k < 32; ++k) {
                float a0 = A[tr * 4 + 0][k0 + k];
                float a1 = A[tr * 4 + 1][k0 + k];
                float a2 = A[tr * 4 + 2][k0 + k];
                float a3 = A[tr * 4 + 3][k0 + k];
                float4 b0 = *(const float4*)&Wc[k][tc * 8];
                float4 b1 = *(const float4*)&Wc[k][tc * 8 + 4];
                float bv[8] = {b0.x, b0.y, b0.z, b0.w, b1.x, b1.y, b1.z, b1.w};
#pragma unroll
                for (int c = 0; c < 8; ++c) {
                    acc[0][c] += a0 * bv[c];
                    acc[1][c] += a1 * bv[c];
                    acc[2][c] += a2 * bv[c];
                    acc[3][c] += a3 * bv[c];
                }
            }
            __syncthreads();
        }
    }

#pragma unroll
    for (int j = 0; j < 4; ++j) {
        int n = n0 + tr * 4 + j;
        if (n < N_NODES) {
            float4 o0, o1;
            float v;
            v = acc[j][0] + bs[tc * 8 + 0]; o0.x = v > 0.f ? v : 0.f;
            v = acc[j][1] + bs[tc * 8 + 1]; o0.y = v > 0.f ? v : 0.f;
            v = acc[j][2] + bs[tc * 8 + 2]; o0.z = v > 0.f ? v : 0.f;
            v = acc[j][3] + bs[tc * 8 + 3]; o0.w = v > 0.f ? v : 0.f;
            v = acc[j][4] + bs[tc * 8 + 4]; o1.x = v > 0.f ? v : 0.f;
            v = acc[j][5] + bs[tc * 8 + 5]; o1.y = v > 0.f ? v : 0.f;
            v = acc[j][6] + bs[tc * 8 + 6]; o1.z = v > 0.f ? v : 0.f;
            v = acc[j][7] + bs[tc * 8 + 7]; o1.w = v > 0.f ? v : 0.f;
            float4* op = (float4*)(out + (size_t)n * D + tc * 8);
            op[0] = o0;
            op[1] = o1;
        }
    }
}

extern "C" void kernel_launch(void* const* d_in, const int* in_sizes, int n_in,
                              void* d_out, int out_size, void* d_ws, size_t ws_size,
                              hipStream_t stream) {
    const float* x     = (const float*)d_in[0];
    const int*   ei    = (const int*)d_in[1];
    const int*   et    = (const int*)d_in[2];
    const float* W     = (const float*)d_in[3];
    const float* Wroot = (const float*)d_in[4];
    const float* b     = (const float*)d_in[5];
    float* out = (float*)d_out;
    int* ws = (int*)d_ws;
    int* off = ws;            // NR ints
    int* bucket = ws + NR;    // E ints (scan partials alias its head)

    hipMemsetAsync(d_ws, 0, (size_t)NR * sizeof(int), stream);

    count_kernel<<<(E_EDGES + 255) / 256, 256, 0, stream>>>(ei, et, off);
    scan1_kernel<<<SCAN_BLOCKS, 256, 0, stream>>>(off, bucket);
    scan2_kernel<<<1, 512, 0, stream>>>(bucket);
    scan3_kernel<<<SCAN_BLOCKS, 256, 0, stream>>>(off, bucket);
    bucket_kernel<<<(E_EDGES + 255) / 256, 256, 0, stream>>>(ei, et, off, bucket);
    fused_kernel<<<(N_NODES + 63) / 64, 256, 0, stream>>>(x, W, Wroot, b, off,
                                                          bucket, out);
}

// Round 4
// 370.713 us; speedup vs baseline: 5.9546x; 1.1444x over previous
//
#include <hip/hip_runtime.h>

#define N_NODES 50000
#define D 128
#define R 8
#define E_EDGES 600000
#define NR (N_NODES * R)                 // 400000 (rel,dst) keys: key = r*N + dst
#define SCAN_BLOCKS ((NR + 1023) / 1024) // 391

// ws layout (ints): [0, NR) = counts -> exclusive offsets -> segment ENDS
//                   [NR, NR+E) = bucket (src node per edge, (rel,dst)-sorted);
//                   scan partials alias the bucket region (used before bucket fill)

__global__ void __launch_bounds__(256)
count_kernel(const int* __restrict__ ei, const int* __restrict__ et,
             int* __restrict__ cnt) {
    int e = blockIdx.x * 256 + threadIdx.x;
    if (e < E_EDGES) {
        int dst = ei[E_EDGES + e];
        int r = et[e];
        atomicAdd(&cnt[r * N_NODES + dst], 1);
    }
}

// Block-local exclusive scan over 1024 counts; per-block total -> part[]
__global__ void __launch_bounds__(256)
scan1_kernel(int* __restrict__ off, int* __restrict__ part) {
    __shared__ int wsum[4];
    int tid = threadIdx.x, lane = tid & 63, wid = tid >> 6;
    int base = blockIdx.x * 1024 + tid * 4;
    int c0 = 0, c1 = 0, c2 = 0, c3 = 0;
    if (base + 0 < NR) c0 = off[base + 0];
    if (base + 1 < NR) c1 = off[base + 1];
    if (base + 2 < NR) c2 = off[base + 2];
    if (base + 3 < NR) c3 = off[base + 3];
    int ts = c0 + c1 + c2 + c3;
    int v = ts;
#pragma unroll
    for (int o = 1; o < 64; o <<= 1) {
        int u = __shfl_up(v, o, 64);
        if (lane >= o) v += u;
    }
    if (lane == 63) wsum[wid] = v;
    __syncthreads();
    int wbase = 0;
#pragma unroll
    for (int w = 0; w < 4; ++w)
        if (w < wid) wbase += wsum[w];
    int excl = wbase + v - ts;
    if (base + 0 < NR) off[base + 0] = excl;
    if (base + 1 < NR) off[base + 1] = excl + c0;
    if (base + 2 < NR) off[base + 2] = excl + c0 + c1;
    if (base + 3 < NR) off[base + 3] = excl + c0 + c1 + c2;
    if (tid == 0) part[blockIdx.x] = wsum[0] + wsum[1] + wsum[2] + wsum[3];
}

__global__ void __launch_bounds__(512)
scan2_kernel(int* __restrict__ part) {
    __shared__ int sp[SCAN_BLOCKS];
    int tid = threadIdx.x;
    if (tid < SCAN_BLOCKS) sp[tid] = part[tid];
    __syncthreads();
    if (tid == 0) {
        int acc = 0;
        for (int i = 0; i < SCAN_BLOCKS; ++i) { int t = sp[i]; sp[i] = acc; acc += t; }
    }
    __syncthreads();
    if (tid < SCAN_BLOCKS) part[tid] = sp[tid];
}

__global__ void __launch_bounds__(256)
scan3_kernel(int* __restrict__ off, const int* __restrict__ part) {
    int p = part[blockIdx.x];
    int base = blockIdx.x * 1024 + threadIdx.x * 4;
#pragma unroll
    for (int i = 0; i < 4; ++i)
        if (base + i < NR) off[base + i] += p;
}

// Scatter src ids into (rel,dst)-sorted bucket. Turns off[] into segment ENDS.
__global__ void __launch_bounds__(256)
bucket_kernel(const int* __restrict__ ei, const int* __restrict__ et,
              int* __restrict__ off, int* __restrict__ bucket) {
    int e = blockIdx.x * 256 + threadIdx.x;
    if (e < E_EDGES) {
        int src = ei[e];
        int dst = ei[E_EDGES + e];
        int r = et[e];
        int key = r * N_NODES + dst;
        int pos = atomicAdd(&off[key], 1);
        bucket[pos] = src;
    }
}

// One block = 64 dst nodes. For r=0..7: At[k][dst] = per-(dst,r) mean of x_src,
// acc += At^T-slice @ W[r]. r=8: At = x[dst], W_root. Then +bias, ReLU, one
// coalesced non-atomic write per out row.
// LDS geometry (all accesses <=2-way => conflict-free per m136):
//   At[128][64]: gather writes = 64 lanes stride-1 b32; GEMM reads = broadcast b128
//   Wc[32][128]: stage = coalesced b128; reads = 32 lanes x 16B = full-bank sweep
__global__ void __launch_bounds__(256, 3)
fused_kernel(const float* __restrict__ x, const float* __restrict__ W,
             const float* __restrict__ Wroot, const float* __restrict__ bias,
             const int* __restrict__ ends, const int* __restrict__ bucket,
             float* __restrict__ out) {
    __shared__ __align__(16) float At[128][64];   // [k][dst], 32 KB
    __shared__ __align__(16) float Wc[32][128];   // staged W k-chunk, 16 KB
    __shared__ float bs[128];

    int tid = threadIdx.x;
    if (tid < 128) bs[tid] = bias[tid];
    int tc = tid & 31;        // GEMM: col group (4 cols: tc*4..+3)
    int tr = tid >> 5;        // GEMM: row group (8 rows: tr*8..+7)
    int gd = tid & 63;        // gather: dst slot 0..63 (lane == dst)
    int gq = tid >> 6;        // gather: 32-col quarter (wave == quarter)
    int n0 = blockIdx.x * 64;
    int n = n0 + gd;

    float acc[8][4];
#pragma unroll
    for (int j = 0; j < 8; ++j)
#pragma unroll
        for (int c = 0; c < 4; ++c) acc[j][c] = 0.0f;

    for (int r = 0; r < 9; ++r) {
        float ga[32];
#pragma unroll
        for (int c = 0; c < 32; ++c) ga[c] = 0.0f;
        if (r < 8) {
            if (n < N_NODES) {
                int key = r * N_NODES + n;
                int s = (key == 0) ? 0 : ends[key - 1];
                int epos = ends[key];
                float inv = (epos > s) ? 1.0f / (float)(epos - s) : 0.0f;
                for (int p = s; p < epos; ++p) {
                    int src = bucket[p];
                    const float4* xp = (const float4*)(x + (size_t)src * D + gq * 32);
#pragma unroll
                    for (int u = 0; u < 8; ++u) {
                        float4 v = xp[u];
                        ga[u * 4 + 0] += v.x; ga[u * 4 + 1] += v.y;
                        ga[u * 4 + 2] += v.z; ga[u * 4 + 3] += v.w;
                    }
                }
#pragma unroll
                for (int c = 0; c < 32; ++c) ga[c] *= inv;
            }
        } else {
            if (n < N_NODES) {
                const float4* xp = (const float4*)(x + (size_t)n * D + gq * 32);
#pragma unroll
                for (int u = 0; u < 8; ++u) {
                    float4 v = xp[u];
                    ga[u * 4 + 0] = v.x; ga[u * 4 + 1] = v.y;
                    ga[u * 4 + 2] = v.z; ga[u * 4 + 3] = v.w;
                }
            }
        }
        __syncthreads();  // previous rel's GEMM done reading At/Wc
#pragma unroll
        for (int c = 0; c < 32; ++c) At[gq * 32 + c][gd] = ga[c];
        __syncthreads();

        const float* Wr = (r < 8) ? (W + (size_t)r * D * D) : Wroot;
        for (int k0 = 0; k0 < D; k0 += 32) {
            const float4* s4 = (const float4*)(Wr + (size_t)k0 * D);
            float4* d4 = (float4*)&Wc[0][0];
#pragma unroll
            for (int u = 0; u < 4; ++u) d4[tid + u * 256] = s4[tid + u * 256];
            __syncthreads();
#pragma unroll
            for (int k = 0; k < 32; ++k) {
                float4 a0 = *(const float4*)&At[k0 + k][tr * 8];
                float4 a1 = *(const float4*)&At[k0 + k][tr * 8 + 4];
                float4 bv = *(const float4*)&Wc[k][tc * 4];
                float a[8] = {a0.x, a0.y, a0.z, a0.w, a1.x, a1.y, a1.z, a1.w};
#pragma unroll
                for (int j = 0; j < 8; ++j) {
                    acc[j][0] += a[j] * bv.x;
                    acc[j][1] += a[j] * bv.y;
                    acc[j][2] += a[j] * bv.z;
                    acc[j][3] += a[j] * bv.w;
                }
            }
            __syncthreads();
        }
    }

#pragma unroll
    for (int j = 0; j < 8; ++j) {
        int nn = n0 + tr * 8 + j;
        if (nn < N_NODES) {
            float4 o;
            float v;
            v = acc[j][0] + bs[tc * 4 + 0]; o.x = v > 0.f ? v : 0.f;
            v = acc[j][1] + bs[tc * 4 + 1]; o.y = v > 0.f ? v : 0.f;
            v = acc[j][2] + bs[tc * 4 + 2]; o.z = v > 0.f ? v : 0.f;
            v = acc[j][3] + bs[tc * 4 + 3]; o.w = v > 0.f ? v : 0.f;
            *(float4*)(out + (size_t)nn * D + tc * 4) = o;
        }
    }
}

extern "C" void kernel_launch(void* const* d_in, const int* in_sizes, int n_in,
                              void* d_out, int out_size, void* d_ws, size_t ws_size,
                              hipStream_t stream) {
    const float* x     = (const float*)d_in[0];
    const int*   ei    = (const int*)d_in[1];
    const int*   et    = (const int*)d_in[2];
    const float* W     = (const float*)d_in[3];
    const float* Wroot = (const float*)d_in[4];
    const float* b     = (const float*)d_in[5];
    float* out = (float*)d_out;
    int* ws = (int*)d_ws;
    int* off = ws;            // NR ints
    int* bucket = ws + NR;    // E ints (scan partials alias its head)

    hipMemsetAsync(d_ws, 0, (size_t)NR * sizeof(int), stream);

    count_kernel<<<(E_EDGES + 255) / 256, 256, 0, stream>>>(ei, et, off);
    scan1_kernel<<<SCAN_BLOCKS, 256, 0, stream>>>(off, bucket);
    scan2_kernel<<<1, 512, 0, stream>>>(bucket);
    scan3_kernel<<<SCAN_BLOCKS, 256, 0, stream>>>(off, bucket);
    bucket_kernel<<<(E_EDGES + 255) / 256, 256, 0, stream>>>(ei, et, off, bucket);
    fused_kernel<<<(N_NODES + 63) / 64, 256, 0, stream>>>(x, W, Wroot, b, off,
                                                          bucket, out);
}